// Round 1
// baseline (764.718 us; speedup 1.0000x reference)
//
#include <hip/hip_runtime.h>
#include <cstdint>
#include <cstddef>

typedef unsigned short u16;
typedef __attribute__((ext_vector_type(8))) __bf16 bf16x8;
typedef __attribute__((ext_vector_type(4))) float f32x4;
typedef __attribute__((ext_vector_type(8))) unsigned short u16x8;
typedef __attribute__((ext_vector_type(4))) unsigned short u16x4;

__device__ __forceinline__ u16 f2bf(float f) {
  union { float f; unsigned u; } v; v.f = f;
  unsigned r = v.u + 0x7fffu + ((v.u >> 16) & 1u);   // RNE
  return (u16)(r >> 16);
}
__device__ __forceinline__ float bf2f(u16 x) {
  union { float f; unsigned u; } v; v.u = ((unsigned)x) << 16;
  return v.f;
}

__device__ __forceinline__ void gll16(const void* g, void* l) {
  __builtin_amdgcn_global_load_lds(
      (const __attribute__((address_space(1))) void*)g,
      (__attribute__((address_space(3))) void*)l, 16, 0, 0);
}

// ---------------------------------------------------------------------------
// x (f32) -> bf16
__global__ __launch_bounds__(256) void cvt_x(const float* __restrict__ x,
                                             u16* __restrict__ xb, int n) {
  int i = (blockIdx.x * 256 + threadIdx.x) * 4;
  if (i < n) {
    float4 v = *(const float4*)(x + i);
    u16x4 o = { f2bf(v.x), f2bf(v.y), f2bf(v.z), f2bf(v.w) };
    *(u16x4*)(xb + i) = o;
  }
}

// ---------------------------------------------------------------------------
// Build W3^T (3072 x 1024) bf16: rows n<1024 = Wq col n; n<2048 = K col; else V col.
__global__ __launch_bounds__(256) void build_w3t(const float* __restrict__ Wq,
                                                 const float* __restrict__ Wkv,
                                                 u16* __restrict__ W3t) {
  __shared__ float tile[32][33];
  int bx = blockIdx.x, by = blockIdx.y;          // bx: n-tile (96), by: k-tile (32)
  int tx = threadIdx.x & 31, tyb = threadIdx.x >> 5;
  int n = bx * 32 + tx;
  const float* src; int scol, sld;
  if (n < 1024)      { src = Wq;  scol = n;                                   sld = 1024; }
  else if (n < 2048) { int m = n - 1024; src = Wkv; scol = (m >> 6) * 128 + (m & 63);      sld = 2048; }
  else               { int m = n - 2048; src = Wkv; scol = (m >> 6) * 128 + 64 + (m & 63); sld = 2048; }
#pragma unroll
  for (int i = 0; i < 4; ++i) {
    int k = by * 32 + tyb + i * 8;
    tile[tyb + i * 8][tx] = src[(size_t)k * sld + scol];
  }
  __syncthreads();
#pragma unroll
  for (int i = 0; i < 4; ++i) {
    int n2 = bx * 32 + tyb + i * 8;
    int k2 = by * 32 + tx;
    W3t[(size_t)n2 * 1024 + k2] = f2bf(tile[tx][tyb + i * 8]);
  }
}

// ---------------------------------------------------------------------------
// m97-style bf16 GEMM: C[m][n] = sum_k A[m][k] * Bt[n][k].
// 128x128 tile, BK=32, 256 threads (2x2 waves, 4x4 16x16x32 MFMA frags/wave).
// MODE 1: epilogue QKV (Q: row-softmax*SCALE -> bf16 L; K: exp -> bf16 L + Z atomics;
//                      V: bf16 L).  ldc=3072.
// MODE 2: f32 out + bias, Bt batched by token-row / 8192.
template <int MODE>
__global__ __launch_bounds__(256)
void gemm_bt_k(const u16* __restrict__ A, int lda,
               const u16* __restrict__ Bt0, int ldb, int K,
               u16* __restrict__ Lout, int ldc,
               float* __restrict__ Fout,
               float* __restrict__ Zp, const float* __restrict__ bias,
               size_t bstride, int rows_per_batch) {
  __shared__ u16 As[128 * 32];
  __shared__ u16 Bs[128 * 32];
  const int tid  = threadIdx.x;
  const int lane = tid & 63, wave = tid >> 6;
  const int wm = wave >> 1, wn = wave & 1;
  const int tileM = blockIdx.y * 128, tileN = blockIdx.x * 128;

  const u16* Bt = Bt0;
  if (MODE == 2) Bt += (size_t)(tileM / rows_per_batch) * bstride;

  // staging: chunk c in {0,1} per wave; lane loads 16B
  const int srow = lane >> 2;               // 0..15
  const int scol = (lane & 3) * 8;          // elem col in [0,32)
  const size_t arow0 = (size_t)(tileM + wave * 32 + srow);
  const size_t brow0 = (size_t)(tileN + wave * 32 + srow);
  const u16* aptr0 = A  + arow0 * lda + scol;
  const u16* aptr1 = A  + (arow0 + 16) * lda + scol;
  const u16* bptr0 = Bt + brow0 * ldb + scol;
  const u16* bptr1 = Bt + (brow0 + 16) * ldb + scol;
  char* asl = (char*)As + wave * 2048;
  char* bsl = (char*)Bs + wave * 2048;

  int aoff[4], boff[4];
#pragma unroll
  for (int i = 0; i < 4; ++i) {
    aoff[i] = (wm * 64 + i * 16 + (lane & 15)) * 32 + (lane >> 4) * 8;
    boff[i] = (wn * 64 + i * 16 + (lane & 15)) * 32 + (lane >> 4) * 8;
  }

  f32x4 acc[4][4];
#pragma unroll
  for (int i = 0; i < 4; ++i)
#pragma unroll
    for (int j = 0; j < 4; ++j) acc[i][j] = (f32x4){0.f, 0.f, 0.f, 0.f};

  for (int k0 = 0; k0 < K; k0 += 32) {
    gll16(aptr0 + k0, asl);
    gll16(aptr1 + k0, asl + 1024);
    gll16(bptr0 + k0, bsl);
    gll16(bptr1 + k0, bsl + 1024);
    __syncthreads();
    bf16x8 af[4], bf[4];
#pragma unroll
    for (int i = 0; i < 4; ++i) af[i] = *(const bf16x8*)(As + aoff[i]);
#pragma unroll
    for (int i = 0; i < 4; ++i) bf[i] = *(const bf16x8*)(Bs + boff[i]);
#pragma unroll
    for (int mi = 0; mi < 4; ++mi)
#pragma unroll
      for (int ni = 0; ni < 4; ++ni)
        acc[mi][ni] = __builtin_amdgcn_mfma_f32_16x16x32_bf16(af[mi], bf[ni], acc[mi][ni], 0, 0, 0);
    __syncthreads();
  }

  const int colBase = tileN + wn * 64;
  const int rowBase = tileM + wm * 64;
  const int q = lane >> 4, cl = lane & 15;

  if (MODE == 1) {
    if (colBase < 1024) {
      // Q region: softmax over the 64-col head chunk, per output row, then *SCALE
#pragma unroll
      for (int mi = 0; mi < 4; ++mi) {
#pragma unroll
        for (int r = 0; r < 4; ++r) {
          float v0 = acc[mi][0][r], v1 = acc[mi][1][r], v2 = acc[mi][2][r], v3 = acc[mi][3][r];
          float mx = fmaxf(fmaxf(v0, v1), fmaxf(v2, v3));
          mx = fmaxf(mx, __shfl_xor(mx, 1));
          mx = fmaxf(mx, __shfl_xor(mx, 2));
          mx = fmaxf(mx, __shfl_xor(mx, 4));
          mx = fmaxf(mx, __shfl_xor(mx, 8));
          float e0 = __expf(v0 - mx), e1 = __expf(v1 - mx);
          float e2 = __expf(v2 - mx), e3 = __expf(v3 - mx);
          float s = e0 + e1 + e2 + e3;
          s += __shfl_xor(s, 1); s += __shfl_xor(s, 2);
          s += __shfl_xor(s, 4); s += __shfl_xor(s, 8);
          float inv = 0.125f / s;   // SCALE = DH^-0.5 = 0.125
          int row = rowBase + mi * 16 + q * 4 + r;
          size_t base = (size_t)row * ldc + colBase + cl;
          Lout[base +  0] = f2bf(e0 * inv);
          Lout[base + 16] = f2bf(e1 * inv);
          Lout[base + 32] = f2bf(e2 * inv);
          Lout[base + 48] = f2bf(e3 * inv);
        }
      }
    } else if (colBase < 2048) {
      // K region: exp, store, accumulate column sums Z
      float zp0 = 0.f, zp1 = 0.f, zp2 = 0.f, zp3 = 0.f;
      const int b = tileM / rows_per_batch;
#pragma unroll
      for (int mi = 0; mi < 4; ++mi) {
#pragma unroll
        for (int r = 0; r < 4; ++r) {
          int row = rowBase + mi * 16 + q * 4 + r;
          size_t base = (size_t)row * ldc + colBase + cl;
          float e0 = __expf(acc[mi][0][r]); Lout[base +  0] = f2bf(e0); zp0 += e0;
          float e1 = __expf(acc[mi][1][r]); Lout[base + 16] = f2bf(e1); zp1 += e1;
          float e2 = __expf(acc[mi][2][r]); Lout[base + 32] = f2bf(e2); zp2 += e2;
          float e3 = __expf(acc[mi][3][r]); Lout[base + 48] = f2bf(e3); zp3 += e3;
        }
      }
      float zp[4] = { zp0, zp1, zp2, zp3 };
#pragma unroll
      for (int ni = 0; ni < 4; ++ni) {
        float z = zp[ni];
        z += __shfl_xor(z, 16);
        z += __shfl_xor(z, 32);
        if (q == 0) atomicAdd(&Zp[b * 1024 + (colBase - 1024) + ni * 16 + cl], z);
      }
    } else {
      // V region: plain bf16 store
#pragma unroll
      for (int mi = 0; mi < 4; ++mi) {
#pragma unroll
        for (int r = 0; r < 4; ++r) {
          int row = rowBase + mi * 16 + q * 4 + r;
          size_t base = (size_t)row * ldc + colBase + cl;
#pragma unroll
          for (int ni = 0; ni < 4; ++ni) Lout[base + ni * 16] = f2bf(acc[mi][ni][r]);
        }
      }
    }
  } else {
    // MODE 2: f32 + bias
#pragma unroll
    for (int mi = 0; mi < 4; ++mi) {
#pragma unroll
      for (int r = 0; r < 4; ++r) {
        int row = rowBase + mi * 16 + q * 4 + r;
        size_t base = (size_t)row * ldc + colBase + cl;
#pragma unroll
        for (int ni = 0; ni < 4; ++ni)
          Fout[base + ni * 16] = acc[mi][ni][r] + bias[colBase + cl + ni * 16];
      }
    }
  }
}

// ---------------------------------------------------------------------------
// ctx_raw[b,h,d,e] += sum_s expK[s,d] * V[s,e]  (f32 VALU, S split 16-way, atomics)
__global__ __launch_bounds__(256) void ctx_k(const u16* __restrict__ L,
                                             float* __restrict__ craw) {
  int bh = blockIdx.y, b = bh >> 4, h = bh & 15;
  int s0 = blockIdx.x * 512;
  __shared__ float sK[16][64];
  __shared__ float sV[16][64];
  int t = threadIdx.x;
  int ty = t >> 4, tx = t & 15;
  float acc[4][4] = {};
  const size_t rowb = (size_t)(b * 8192 + s0);
  for (int sb = 0; sb < 512; sb += 16) {
    const u16* src = L + (rowb + sb + ty) * 3072 +
                     (tx < 8 ? (1024 + h * 64 + tx * 8) : (2048 + h * 64 + (tx - 8) * 8));
    u16x8 v = *(const u16x8*)src;
    float* dst = (tx < 8) ? &sK[ty][tx * 8] : &sV[ty][(tx - 8) * 8];
#pragma unroll
    for (int i = 0; i < 8; ++i) dst[i] = bf2f(v[i]);
    __syncthreads();
#pragma unroll
    for (int r = 0; r < 16; ++r) {
      f32x4 kv = *(const f32x4*)&sK[r][ty * 4];
      f32x4 vv = *(const f32x4*)&sV[r][tx * 4];
#pragma unroll
      for (int i = 0; i < 4; ++i)
#pragma unroll
        for (int j = 0; j < 4; ++j) acc[i][j] += kv[i] * vv[j];
    }
    __syncthreads();
  }
  float* dstc = craw + ((size_t)bh * 64 + ty * 4) * 64 + tx * 4;
#pragma unroll
  for (int i = 0; i < 4; ++i)
#pragma unroll
    for (int j = 0; j < 4; ++j) atomicAdd(&dstc[i * 64 + j], acc[i][j]);
}

// ctxn = ctx_raw / Z[bh*64+d]
__global__ __launch_bounds__(256) void norm_ctx(const float* __restrict__ craw,
                                                const float* __restrict__ Z,
                                                float* __restrict__ cn) {
  int i = blockIdx.x * 256 + threadIdx.x;  // 262144 total
  cn[i] = craw[i] / Z[i >> 6];
}

// Weff_t[b, j, h*64+d] = sum_e ctxn[b,h,d,e] * Wlin[h*64+e, j]   (bf16 out)
__global__ __launch_bounds__(256) void weff_k(const float* __restrict__ cn,
                                              const float* __restrict__ Wlin,
                                              u16* __restrict__ Wt) {
  int bh = blockIdx.y; int b = bh >> 4, h = bh & 15;
  int j = blockIdx.x * 256 + threadIdx.x;
  const float* c = cn + (size_t)bh * 4096;
  float out[64];
#pragma unroll
  for (int d = 0; d < 64; ++d) out[d] = 0.f;
  for (int e = 0; e < 64; ++e) {
    float w = Wlin[(size_t)(h * 64 + e) * 1024 + j];
#pragma unroll
    for (int d = 0; d < 64; ++d) out[d] += c[d * 64 + e] * w;
  }
  u16* dst = Wt + ((size_t)b * 1024 + j) * 1024 + h * 64;
#pragma unroll
  for (int d = 0; d < 64; ++d) dst[d] = f2bf(out[d]);
}

// ---------------------------------------------------------------------------
extern "C" void kernel_launch(void* const* d_in, const int* in_sizes, int n_in,
                              void* d_out, int out_size, void* d_ws, size_t ws_size,
                              hipStream_t stream) {
  const float* x    = (const float*)d_in[0];
  const float* Wq   = (const float*)d_in[1];
  const float* Wkv  = (const float*)d_in[2];
  const float* Wlin = (const float*)d_in[3];
  const float* blin = (const float*)d_in[4];
  float* out = (float*)d_out;
  char* ws = (char*)d_ws;

  // workspace layout (272 MB total)
  u16*   xb   = (u16*)(ws);                    // 64 MB  : x as bf16 (32768 x 1024)
  u16*   w3t  = (u16*)(ws + 67108864);         // 6 MB   : W3^T bf16 (3072 x 1024)
  u16*   L    = (u16*)(ws + 73400320);         // 192 MB : [Qs | expK | V] bf16 (32768 x 3072)
  float* Zp   = (float*)(ws + 274726912);      // 16 KB  : K-softmax denominators (4 x 1024)
  float* craw = (float*)(ws + 274743296);      // 1 MB   : ctx_raw (64 x 64 x 64)
  float* cn   = (float*)(ws + 275791872);      // 1 MB   : ctx normalized
  u16*   weff = (u16*)(ws + 276840448);        // 8 MB   : Weff^T bf16 (4 x 1024 x 1024)

  hipMemsetAsync(Zp, 0, 16384 + 1048576, stream);  // zero Z + ctx_raw (adjacent)

  cvt_x<<<32768, 256, 0, stream>>>(x, xb, 33554432);
  build_w3t<<<dim3(96, 32), 256, 0, stream>>>(Wq, Wkv, w3t);

  // GEMM1: logits + fused softmax/exp epilogue -> L, Z
  gemm_bt_k<1><<<dim3(24, 256), 256, 0, stream>>>(
      xb, 1024, w3t, 1024, 1024, L, 3072, nullptr, Zp, nullptr, (size_t)0, 8192);

  ctx_k<<<dim3(16, 64), 256, 0, stream>>>(L, craw);
  norm_ctx<<<1024, 256, 0, stream>>>(craw, Zp, cn);
  weff_k<<<dim3(4, 64), 256, 0, stream>>>(cn, Wlin, weff);

  // GEMM2: out = Qs @ Weff[b] + blin  (f32 out)
  gemm_bt_k<2><<<dim3(8, 256), 256, 0, stream>>>(
      L, 3072, weff, 1024, 1024, nullptr, 1024, out, nullptr, blin, (size_t)1048576, 8192);
}

// Round 2
// 739.751 us; speedup vs baseline: 1.0337x; 1.0337x over previous
//
#include <hip/hip_runtime.h>
#include <cstdint>
#include <cstddef>

typedef unsigned short u16;
typedef unsigned int u32;
typedef __attribute__((ext_vector_type(8))) __bf16 bf16x8;
typedef __attribute__((ext_vector_type(4))) float f32x4;
typedef __attribute__((ext_vector_type(8))) unsigned short u16x8;
typedef __attribute__((ext_vector_type(4))) unsigned short u16x4;

__device__ __forceinline__ u16 f2bf(float f) {
  union { float f; unsigned u; } v; v.f = f;
  unsigned r = v.u + 0x7fffu + ((v.u >> 16) & 1u);   // RNE
  return (u16)(r >> 16);
}
__device__ __forceinline__ float bf2f(u16 x) {
  union { float f; unsigned u; } v; v.u = ((unsigned)x) << 16;
  return v.f;
}
// pack two f32 -> two bf16 (RNE); compiler fuses the merge into v_perm_b32
__device__ __forceinline__ u32 pk2(float a, float b) {
  union { float f; unsigned u; } x, y; x.f = a; y.f = b;
  unsigned ra = x.u + 0x7fffu + ((x.u >> 16) & 1u);
  unsigned rb = y.u + 0x7fffu + ((y.u >> 16) & 1u);
  return (ra >> 16) | (rb & 0xffff0000u);
}

__device__ __forceinline__ void gll16(const void* g, void* l) {
  __builtin_amdgcn_global_load_lds(
      (const __attribute__((address_space(1))) void*)g,
      (__attribute__((address_space(3))) void*)l, 16, 0, 0);
}

// ---------------------------------------------------------------------------
// x (f32) -> bf16
__global__ __launch_bounds__(256) void cvt_x(const float* __restrict__ x,
                                             u16* __restrict__ xb, int n) {
  int i = (blockIdx.x * 256 + threadIdx.x) * 4;
  if (i < n) {
    float4 v = *(const float4*)(x + i);
    u16x4 o = { f2bf(v.x), f2bf(v.y), f2bf(v.z), f2bf(v.w) };
    *(u16x4*)(xb + i) = o;
  }
}

// ---------------------------------------------------------------------------
// W3^T (3072 x 1024) bf16, with per-64-chunk column permutation baked in:
// physical row n holds LOGICAL column (n&~63) | lam(n&63), lam(u)=(u&15)*4+(u>>4).
// With this, GEMM epilogue lane cl's 4 frag values are logical cols cl*4+{0..3}
// -> contiguous 8B stores, and L stays in NATURAL column order.
__global__ __launch_bounds__(256) void build_w3t(const float* __restrict__ Wq,
                                                 const float* __restrict__ Wkv,
                                                 u16* __restrict__ W3t) {
  __shared__ float tile[32][33];
  int bx = blockIdx.x, by = blockIdx.y;          // bx: n-tile (96), by: k-tile (32)
  int tx = threadIdx.x & 31, tyb = threadIdx.x >> 5;
  int n = bx * 32 + tx;                          // physical row
  int u = n & 63;
  int nl = (n & ~63) | ((u & 15) << 2) | (u >> 4);  // logical column
  const float* src; int scol, sld;
  if (nl < 1024)      { src = Wq;  scol = nl;                                  sld = 1024; }
  else if (nl < 2048) { int m = nl - 1024; src = Wkv; scol = (m >> 6) * 128 + (m & 63);      sld = 2048; }
  else                { int m = nl - 2048; src = Wkv; scol = (m >> 6) * 128 + 64 + (m & 63); sld = 2048; }
#pragma unroll
  for (int i = 0; i < 4; ++i) {
    int k = by * 32 + tyb + i * 8;
    tile[tyb + i * 8][tx] = src[(size_t)k * sld + scol];
  }
  __syncthreads();
#pragma unroll
  for (int i = 0; i < 4; ++i) {
    int n2 = bx * 32 + tyb + i * 8;
    int k2 = by * 32 + tx;
    W3t[(size_t)n2 * 1024 + k2] = f2bf(tile[tx][tyb + i * 8]);
  }
}

// ---------------------------------------------------------------------------
// m97-style bf16 GEMM, Bt rows permuted per 64-chunk (see build_w3t).
// MODE 1: epilogue QKV (Q: row-softmax*SCALE; K: exp + Z col-sums; V: raw) -> bf16 L
// MODE 2: f32 out + bias, Bt batched by tileM/rows_per_batch.
template <int MODE>
__global__ __launch_bounds__(256)
void gemm_bt_k(const u16* __restrict__ A, int lda,
               const u16* __restrict__ Bt0, int ldb, int K,
               u16* __restrict__ Lout, int ldc,
               float* __restrict__ Fout,
               float* __restrict__ Zp, const float* __restrict__ bias,
               size_t bstride, int rows_per_batch) {
  __shared__ u16 As[128 * 32];
  __shared__ u16 Bs[128 * 32];
  const int tid  = threadIdx.x;
  const int lane = tid & 63, wave = tid >> 6;
  const int wm = wave >> 1, wn = wave & 1;
  const int tileM = blockIdx.y * 128, tileN = blockIdx.x * 128;

  const u16* Bt = Bt0;
  if (MODE == 2) Bt += (size_t)(tileM / rows_per_batch) * bstride;

  const int srow = lane >> 2;               // 0..15
  const int scol = (lane & 3) * 8;          // elem col in [0,32)
  const size_t arow0 = (size_t)(tileM + wave * 32 + srow);
  const size_t brow0 = (size_t)(tileN + wave * 32 + srow);
  const u16* aptr0 = A  + arow0 * lda + scol;
  const u16* aptr1 = A  + (arow0 + 16) * lda + scol;
  const u16* bptr0 = Bt + brow0 * ldb + scol;
  const u16* bptr1 = Bt + (brow0 + 16) * ldb + scol;
  char* asl = (char*)As + wave * 2048;
  char* bsl = (char*)Bs + wave * 2048;

  int aoff[4], boff[4];
#pragma unroll
  for (int i = 0; i < 4; ++i) {
    aoff[i] = (wm * 64 + i * 16 + (lane & 15)) * 32 + (lane >> 4) * 8;
    boff[i] = (wn * 64 + i * 16 + (lane & 15)) * 32 + (lane >> 4) * 8;
  }

  f32x4 acc[4][4];
#pragma unroll
  for (int i = 0; i < 4; ++i)
#pragma unroll
    for (int j = 0; j < 4; ++j) acc[i][j] = (f32x4){0.f, 0.f, 0.f, 0.f};

  for (int k0 = 0; k0 < K; k0 += 32) {
    gll16(aptr0 + k0, asl);
    gll16(aptr1 + k0, asl + 1024);
    gll16(bptr0 + k0, bsl);
    gll16(bptr1 + k0, bsl + 1024);
    __syncthreads();
    bf16x8 af[4], bfr[4];
#pragma unroll
    for (int i = 0; i < 4; ++i) af[i] = *(const bf16x8*)(As + aoff[i]);
#pragma unroll
    for (int i = 0; i < 4; ++i) bfr[i] = *(const bf16x8*)(Bs + boff[i]);
#pragma unroll
    for (int mi = 0; mi < 4; ++mi)
#pragma unroll
      for (int ni = 0; ni < 4; ++ni)
        acc[mi][ni] = __builtin_amdgcn_mfma_f32_16x16x32_bf16(af[mi], bfr[ni], acc[mi][ni], 0, 0, 0);
    __syncthreads();
  }

  const int colBase = tileN + wn * 64;
  const int rowBase = tileM + wm * 64;
  const int q = lane >> 4, cl = lane & 15;

  if (MODE == 1) {
    if (colBase < 1024) {
      // Q: softmax over the 64-col head chunk (no max-sub: |logit| < ~4), *SCALE
#pragma unroll
      for (int mi = 0; mi < 4; ++mi) {
#pragma unroll
        for (int r = 0; r < 4; ++r) {
          float e0 = __expf(acc[mi][0][r]), e1 = __expf(acc[mi][1][r]);
          float e2 = __expf(acc[mi][2][r]), e3 = __expf(acc[mi][3][r]);
          float s = (e0 + e1) + (e2 + e3);
          s += __shfl_xor(s, 1); s += __shfl_xor(s, 2);
          s += __shfl_xor(s, 4); s += __shfl_xor(s, 8);
          float inv = 0.125f / s;   // SCALE = DH^-0.5
          int row = rowBase + mi * 16 + q * 4 + r;
          uint2 pv = { pk2(e0 * inv, e1 * inv), pk2(e2 * inv, e3 * inv) };
          *(uint2*)(Lout + (size_t)row * ldc + colBase + cl * 4) = pv;
        }
      }
    } else if (colBase < 2048) {
      // K: exp, packed store, accumulate column sums Z (logical col = cl*4+ni)
      float zp0 = 0.f, zp1 = 0.f, zp2 = 0.f, zp3 = 0.f;
      const int b = tileM / rows_per_batch;
#pragma unroll
      for (int mi = 0; mi < 4; ++mi) {
#pragma unroll
        for (int r = 0; r < 4; ++r) {
          float e0 = __expf(acc[mi][0][r]), e1 = __expf(acc[mi][1][r]);
          float e2 = __expf(acc[mi][2][r]), e3 = __expf(acc[mi][3][r]);
          zp0 += e0; zp1 += e1; zp2 += e2; zp3 += e3;
          int row = rowBase + mi * 16 + q * 4 + r;
          uint2 pv = { pk2(e0, e1), pk2(e2, e3) };
          *(uint2*)(Lout + (size_t)row * ldc + colBase + cl * 4) = pv;
        }
      }
      float zp[4] = { zp0, zp1, zp2, zp3 };
#pragma unroll
      for (int ni = 0; ni < 4; ++ni) {
        float z = zp[ni];
        z += __shfl_xor(z, 16);
        z += __shfl_xor(z, 32);
        if (q == 0) atomicAdd(&Zp[b * 1024 + (colBase - 1024) + cl * 4 + ni], z);
      }
    } else {
      // V: packed bf16 store
#pragma unroll
      for (int mi = 0; mi < 4; ++mi) {
#pragma unroll
        for (int r = 0; r < 4; ++r) {
          int row = rowBase + mi * 16 + q * 4 + r;
          uint2 pv = { pk2(acc[mi][0][r], acc[mi][1][r]),
                       pk2(acc[mi][2][r], acc[mi][3][r]) };
          *(uint2*)(Lout + (size_t)row * ldc + colBase + cl * 4) = pv;
        }
      }
    }
  } else {
    // MODE 2: f32 + bias, float4 coalesced stores (logical col = cl*4+ni)
    const float4 bb = *(const float4*)(bias + colBase + cl * 4);
#pragma unroll
    for (int mi = 0; mi < 4; ++mi) {
#pragma unroll
      for (int r = 0; r < 4; ++r) {
        int row = rowBase + mi * 16 + q * 4 + r;
        float4 v = { acc[mi][0][r] + bb.x, acc[mi][1][r] + bb.y,
                     acc[mi][2][r] + bb.z, acc[mi][3][r] + bb.w };
        *(float4*)(Fout + (size_t)row * ldc + colBase + cl * 4) = v;
      }
    }
  }
}

// ---------------------------------------------------------------------------
// ctx partials via MFMA: part[bh][wslot][d][pe] = sum_{s in slot} expK[s,d]*V[s,e]
// pe is the PERMUTED e position: pe = cl*4+ni holds logical e = ni*16+cl.
// Grid (8, 64), 256 thr = 4 waves; each wave owns 256 s (8 chunks of 32).
__global__ __launch_bounds__(256) void ctx_mfma(const u16* __restrict__ L,
                                                float* __restrict__ part) {
  __shared__ __align__(16) u16 kvt[4][2][64 * 40];   // [wave][K/V][d][s], stride 40
  const int bh = blockIdx.y, b = bh >> 4, h = bh & 15;
  const int lane = threadIdx.x & 63, w = threadIdx.x >> 6;
  u16* kt = &kvt[w][0][0];
  u16* vt = &kvt[w][1][0];
  const int sl = lane & 31, half = lane >> 5;
  const int cl = lane & 15, q = lane >> 4;

  f32x4 acc[4][4];
#pragma unroll
  for (int i = 0; i < 4; ++i)
#pragma unroll
    for (int j = 0; j < 4; ++j) acc[i][j] = (f32x4){0.f, 0.f, 0.f, 0.f};

  const int sbase0 = blockIdx.x * 1024 + w * 256;
  for (int c = 0; c < 8; ++c) {
    const size_t rowb = ((size_t)b * 8192 + sbase0 + c * 32 + sl) * 3072;
#pragma unroll
    for (int dblk = 0; dblk < 4; ++dblk) {
      int d0 = dblk * 16 + half * 8;
      u16x8 kv = *(const u16x8*)(L + rowb + 1024 + h * 64 + d0);
      u16x8 vv = *(const u16x8*)(L + rowb + 2048 + h * 64 + d0);
#pragma unroll
      for (int j = 0; j < 8; ++j) {
        kt[(d0 + j) * 40 + sl] = kv[j];
        vt[(d0 + j) * 40 + sl] = vv[j];
      }
    }
    // wave-private LDS region; compiler's lgkmcnt ordering suffices
    bf16x8 af[4], bfr[4];
#pragma unroll
    for (int mi = 0; mi < 4; ++mi) af[mi]  = *(const bf16x8*)&kt[(mi * 16 + cl) * 40 + q * 8];
#pragma unroll
    for (int ni = 0; ni < 4; ++ni) bfr[ni] = *(const bf16x8*)&vt[(ni * 16 + cl) * 40 + q * 8];
#pragma unroll
    for (int mi = 0; mi < 4; ++mi)
#pragma unroll
      for (int ni = 0; ni < 4; ++ni)
        acc[mi][ni] = __builtin_amdgcn_mfma_f32_16x16x32_bf16(af[mi], bfr[ni], acc[mi][ni], 0, 0, 0);
  }

  const int wslot = blockIdx.x * 4 + w;
  float* pb = part + ((size_t)bh * 32 + wslot) * 4096;
#pragma unroll
  for (int mi = 0; mi < 4; ++mi)
#pragma unroll
    for (int r = 0; r < 4; ++r) {
      float4 v = { acc[mi][0][r], acc[mi][1][r], acc[mi][2][r], acc[mi][3][r] };
      *(float4*)(pb + (mi * 16 + q * 4 + r) * 64 + cl * 4) = v;
    }
}

// cn[bh][d][pe] = (sum_w part[bh][w][d][pe]) / Z[b*1024 + h*64 + d]
__global__ __launch_bounds__(256) void norm_ctx(const float* __restrict__ part,
                                                const float* __restrict__ Z,
                                                float* __restrict__ cn) {
  int i = blockIdx.x * 256 + threadIdx.x;   // 262144
  int bh = i >> 12, rest = i & 4095, d = rest >> 6;
  float s = 0.f;
#pragma unroll
  for (int w = 0; w < 32; ++w) s += part[((size_t)bh * 32 + w) * 4096 + rest];
  cn[i] = s / Z[(bh >> 4) * 1024 + (bh & 15) * 64 + d];
}

// Weff_t[b][p][h*64+d] = sum_pe cn[bh][d][pe] * Wlin[(h*64+e(pe))*1024 + lam(p)]
// p is the physical (permuted) output row so GEMM2's epilogue stores float4.
__global__ __launch_bounds__(256) void weff_k(const float* __restrict__ cn,
                                              const float* __restrict__ Wlin,
                                              u16* __restrict__ Wt) {
  int bh = blockIdx.y; int b = bh >> 4, h = bh & 15;
  int p = blockIdx.x * 256 + threadIdx.x;
  int up = p & 63;
  int j = (p & ~63) | ((up & 15) << 2) | (up >> 4);   // logical out col
  const float* c = cn + (size_t)bh * 4096;
  float out[64];
#pragma unroll
  for (int d = 0; d < 64; ++d) out[d] = 0.f;
  for (int pe = 0; pe < 64; ++pe) {
    int e = ((pe & 3) << 4) | (pe >> 2);              // logical e at stored pos pe
    float wv = Wlin[(size_t)(h * 64 + e) * 1024 + j];
#pragma unroll
    for (int d = 0; d < 64; ++d) out[d] += c[d * 64 + pe] * wv;
  }
  u16* dst = Wt + ((size_t)b * 1024 + p) * 1024 + h * 64;
#pragma unroll
  for (int d0 = 0; d0 < 64; d0 += 2)
    *(u32*)(dst + d0) = pk2(out[d0], out[d0 + 1]);
}

// ---------------------------------------------------------------------------
extern "C" void kernel_launch(void* const* d_in, const int* in_sizes, int n_in,
                              void* d_out, int out_size, void* d_ws, size_t ws_size,
                              hipStream_t stream) {
  const float* x    = (const float*)d_in[0];
  const float* Wq   = (const float*)d_in[1];
  const float* Wkv  = (const float*)d_in[2];
  const float* Wlin = (const float*)d_in[3];
  const float* blin = (const float*)d_in[4];
  float* out = (float*)d_out;
  char* ws = (char*)d_ws;

  // phase-1 workspace
  u16*   xb   = (u16*)(ws);                    // 64 MB : x bf16 (32768 x 1024)
  u16*   w3t  = (u16*)(ws + 67108864);         // 6 MB  : W3^T bf16 (3072 x 1024), permuted
  u16*   L    = (u16*)(ws + 73400320);         // 192 MB: [Qs | expK | V] bf16 (32768 x 3072)
  float* Zp   = (float*)(ws + 274726912);      // 16 KB : K-softmax denominators (4 x 1024)
  // phase-2 workspace (reuses xb region; xb is dead after GEMM1)
  float* part = (float*)(ws);                  // 32 MB : ctx partials (64 x 32 x 64 x 64)
  float* cn   = (float*)(ws + 33554432);       // 1 MB  : ctx normalized (permuted e)
  u16*   weff = (u16*)(ws + 34603008);         // 8 MB  : Weff^T bf16 (4 x 1024 x 1024), permuted rows

  hipMemsetAsync(Zp, 0, 16384, stream);

  cvt_x<<<32768, 256, 0, stream>>>(x, xb, 33554432);
  build_w3t<<<dim3(96, 32), 256, 0, stream>>>(Wq, Wkv, w3t);

  gemm_bt_k<1><<<dim3(24, 256), 256, 0, stream>>>(
      xb, 1024, w3t, 1024, 1024, L, 3072, nullptr, Zp, nullptr, (size_t)0, 8192);

  ctx_mfma<<<dim3(8, 64), 256, 0, stream>>>(L, part);
  norm_ctx<<<1024, 256, 0, stream>>>(part, Zp, cn);
  weff_k<<<dim3(4, 64), 256, 0, stream>>>(cn, Wlin, weff);

  gemm_bt_k<2><<<dim3(8, 256), 256, 0, stream>>>(
      L, 3072, weff, 1024, 1024, nullptr, 1024, out, nullptr, blin, (size_t)1048576, 8192);
}